// Round 11
// baseline (129.247 us; speedup 1.0000x reference)
//
#include <hip/hip_runtime.h>

#define B 128
#define N 65536
#define D 512
#define K 5
#define M 256              // D * RATIO
#define GPB 256            // gallery rows per block (kernel1)
#define NBLK1 (N / GPB)    // 256 blocks
#define NW 16              // waves per k1 block

typedef __attribute__((ext_vector_type(8))) short short8;
typedef __attribute__((ext_vector_type(4))) float f32x4;
typedef __attribute__((address_space(1))) const unsigned char as1cu8;
typedef __attribute__((address_space(3))) unsigned char as3u8;

// pack two fp32 -> one u32 of 2 bf16 (truncation) via v_perm_b32.
__device__ __forceinline__ unsigned int pack_bf2(float lo, float hi) {
    return __builtin_amdgcn_perm(__float_as_uint(hi), __float_as_uint(lo), 0x07060302u);
}

__device__ __forceinline__ void top5_insert(float v, int gi, float tv[K], int ti[K]) {
    // descending by value, ties broken by lower index (matches lax.top_k)
    if (v > tv[K - 1] || (v == tv[K - 1] && gi < ti[K - 1])) {
        tv[K - 1] = v; ti[K - 1] = gi;
        #pragma unroll
        for (int k = K - 1; k > 0; --k) {
            bool sw = (tv[k] > tv[k - 1]) || (tv[k] == tv[k - 1] && ti[k] < ti[k - 1]);
            if (sw) {
                float fv = tv[k]; tv[k] = tv[k - 1]; tv[k - 1] = fv;
                int fi = ti[k]; ti[k] = ti[k - 1]; ti[k - 1] = fi;
            }
        }
    }
}

// packed-score insert (meta lives in low 8 mantissa bits; candidates distinct)
__device__ __forceinline__ void pk_insert(float sp, float lst[K]) {
    if (sp > lst[K - 1]) {
        lst[K - 1] = sp;
        #pragma unroll
        for (int k = K - 1; k > 0; --k)
            if (lst[k] > lst[k - 1]) {
                float t2 = lst[k]; lst[k] = lst[k - 1]; lst[k - 1] = t2;
            }
    }
}

// k0t: build t's MFMA B-fragments, bf16, LDS-ready linear layout:
// frag[(bt*16+ks)*64 + lane] = 8 bf16 of t[bt*16 + (lane&15)][ks*32 + (lane>>4)*8 ..+8]
__global__ __launch_bounds__(512) void k0_tfrag(const float* __restrict__ t_f,
                                                uint4* __restrict__ frag) {
    const int q = blockIdx.x * 512 + threadIdx.x;   // 0..8191
    const int bt = q >> 10;
    const int ks = (q >> 6) & 15;
    const int l = q & 63;
    const float* src = t_f + (size_t)(bt * 16 + (l & 15)) * D + ks * 32 + (l >> 4) * 8;
    float4 a = *reinterpret_cast<const float4*>(src);
    float4 b = *reinterpret_cast<const float4*>(src + 4);
    uint4 o;
    o.x = pack_bf2(a.x, a.y); o.y = pack_bf2(a.z, a.w);
    o.z = pack_bf2(b.x, b.y); o.w = pack_bf2(b.z, b.w);
    frag[q] = o;
}

// k1: A = gallery (streamed fp32 -> bf16 in-register), B = t (LDS fragments).
// 16 waves, wave w owns g-rows [blk*256+16w, +16); no barriers in the main
// loop. __launch_bounds__(1024, 4): R10's spill cause was the compiler's
// default 8-waves/EU target capping VGPRs at 64 (demand ~110); 4 waves/EU
// = 1 block/CU (which 128KB LDS forces anyway) -> 128-VGPR cap. lst init
// moved AFTER the MFMA loop to keep its 40 regs dead across the loop.
__global__ __launch_bounds__(1024, 4) void k1_sims(const uint4* __restrict__ frag_t,
                                                   const float* __restrict__ gal,
                                                   float2* __restrict__ partial) {
    __shared__ __align__(16) char smem[NW * 8 * 1024];   // 131072 B: t-frags, then merge buf

    const int tid = threadIdx.x;
    const int blk = blockIdx.x;
    const int lane = tid & 63;
    const int w = tid >> 6;
    const int l15 = lane & 15;
    const int l4 = lane >> 4;

    // ---- stage t-frags: 128KB linear global_load_lds ----
    {
        const char* src = reinterpret_cast<const char*>(frag_t);
        #pragma unroll
        for (int i = 0; i < 8; ++i) {
            const char* s = src + i * 16384 + w * 1024 + lane * 16;
            char* d = smem + i * 16384 + w * 1024;      // wave-uniform; HW adds lane*16
            __builtin_amdgcn_global_load_lds((as1cu8*)s, (as3u8*)d, 16, 0, 0);
        }
    }

    // lane's gallery row + k-quarter
    const int grow = blk * GPB + w * 16 + l15;
    const float* gp = gal + (size_t)grow * D + l4 * 8;

    // issue first k-slice loads before the barrier (overlap DMA drain)
    float4 c0 = *reinterpret_cast<const float4*>(gp);
    float4 c1 = *reinterpret_cast<const float4*>(gp + 4);

    f32x4 acc[8];
    #pragma unroll
    for (int bt = 0; bt < 8; ++bt) acc[bt] = (f32x4)0.0f;
    float nrm = 0.0f;

    __syncthreads();   // t-frags ready (single block-wide barrier)

    #pragma unroll
    for (int ks = 0; ks < 16; ++ks) {
        float4 n0 = c0, n1 = c1;
        if (ks < 15) {
            n0 = *reinterpret_cast<const float4*>(gp + (ks + 1) * 32);
            n1 = *reinterpret_cast<const float4*>(gp + (ks + 1) * 32 + 4);
        }
        nrm = fmaf(c0.x, c0.x, nrm); nrm = fmaf(c0.y, c0.y, nrm);
        nrm = fmaf(c0.z, c0.z, nrm); nrm = fmaf(c0.w, c0.w, nrm);
        nrm = fmaf(c1.x, c1.x, nrm); nrm = fmaf(c1.y, c1.y, nrm);
        nrm = fmaf(c1.z, c1.z, nrm); nrm = fmaf(c1.w, c1.w, nrm);
        uint4 qq;
        qq.x = pack_bf2(c0.x, c0.y); qq.y = pack_bf2(c0.z, c0.w);
        qq.z = pack_bf2(c1.x, c1.y); qq.w = pack_bf2(c1.z, c1.w);
        short8 afrag = *reinterpret_cast<short8*>(&qq);
        #pragma unroll
        for (int bt = 0; bt < 8; ++bt) {
            short8 tf = *reinterpret_cast<const short8*>(smem + (bt * 16 + ks) * 1024 + lane * 16);
            acc[bt] = __builtin_amdgcn_mfma_f32_16x16x32_bf16(afrag, tf, acc[bt], 0, 0, 0);
        }
        c0 = n0; c1 = n1;
    }

    // full row norm: sum the 4 k-quarters (lanes sharing l15)
    nrm += __shfl_xor(nrm, 16);
    nrm += __shfl_xor(nrm, 32);
    float invn = rsqrtf(fmaxf(nrm, 1e-24f));

    // scale for acc row r (g-row l4*4+r): norm lives on lane (l4*4+r)
    float sc[4];
    #pragma unroll
    for (int r = 0; r < 4; ++r) sc[r] = __shfl(invn, l4 * 4 + r);

    // per-b top-5 lists (live range starts HERE, after the MFMA loop)
    float lst[8][K];
    #pragma unroll
    for (int bt = 0; bt < 8; ++bt)
        #pragma unroll
        for (int k = 0; k < K; ++k) lst[bt][k] = -1e30f;

    // insert: candidate g = w*16 + l4*4 + r (8-bit meta within block), per b-list bt
    #pragma unroll
    for (int bt = 0; bt < 8; ++bt)
        #pragma unroll
        for (int r = 0; r < 4; ++r) {
            float s = acc[bt][r] * sc[r];
            unsigned meta = (unsigned)(w * 16 + l4 * 4 + r);
            float sp = __uint_as_float((__float_as_uint(s) & 0xFFFFFF00u) | meta);
            pk_insert(sp, lst[bt]);
        }

    // merge across the 4 lanes sharing l15 (masks 16, 32)
    #pragma unroll
    for (int mk = 16; mk <= 32; mk <<= 1)
        #pragma unroll
        for (int bt = 0; bt < 8; ++bt) {
            float inc[K];
            #pragma unroll
            for (int k = 0; k < K; ++k) inc[k] = __shfl_xor(lst[bt][k], mk);
            #pragma unroll
            for (int k = 0; k < K; ++k) pk_insert(inc[k], lst[bt]);
        }

    // ---- in-block cross-wave merge (smem reused; all t-frag reads done) ----
    __syncthreads();
    float* mbuf = reinterpret_cast<float*>(smem);   // [16 waves][128 b][5]
    if (l4 == 0) {
        #pragma unroll
        for (int bt = 0; bt < 8; ++bt)
            #pragma unroll
            for (int k = 0; k < K; ++k)
                mbuf[((size_t)w * B + bt * 16 + l15) * K + k] = lst[bt][k];
    }
    __syncthreads();
    {
        const int b = tid >> 3, sub = tid & 7;
        float mv[K];
        #pragma unroll
        for (int k = 0; k < K; ++k) mv[k] = -1e30f;
        #pragma unroll
        for (int u = 0; u < 2; ++u) {
            const int wv = sub * 2 + u;
            #pragma unroll
            for (int k = 0; k < K; ++k) pk_insert(mbuf[((size_t)wv * B + b) * K + k], mv);
        }
        #pragma unroll
        for (int mk = 1; mk <= 4; mk <<= 1) {
            float inc[K];
            #pragma unroll
            for (int k = 0; k < K; ++k) inc[k] = __shfl_xor(mv[k], mk);
            #pragma unroll
            for (int k = 0; k < K; ++k) pk_insert(inc[k], mv);
        }
        if (sub == 0) {
            #pragma unroll
            for (int k = 0; k < K; ++k) {
                unsigned sp = __float_as_uint(mv[k]);
                int g = blk * GPB + (int)(sp & 0xFFu);
                partial[((size_t)b * NBLK1 + blk) * K + k] = make_float2(mv[k], __int_as_float(g));
            }
        }
    }
}

// k2: merge 256 partial top-5 lists per batch row -> top_idx. Shuffle-first.
__global__ __launch_bounds__(512) void k2_merge(const float2* __restrict__ partial,
                                                int* __restrict__ top_idx) {
    __shared__ float2 wlist[8][K];
    const int b = blockIdx.x;
    const int p = threadIdx.x;
    const int lane = p & 63;
    const int w = p >> 6;

    float mv[K]; int mi[K];
    #pragma unroll
    for (int k = 0; k < K; ++k) { mv[k] = -1e30f; mi[k] = 0x7fffffff; }
    if (p < NBLK1) {
        #pragma unroll
        for (int k = 0; k < K; ++k) {
            float2 c = partial[((size_t)b * NBLK1 + p) * K + k];
            mv[k] = c.x; mi[k] = __float_as_int(c.y);
        }
    }
    #pragma unroll
    for (int mk = 1; mk <= 32; mk <<= 1) {
        float ov[K]; int oi[K];
        #pragma unroll
        for (int k = 0; k < K; ++k) { ov[k] = __shfl_xor(mv[k], mk); oi[k] = __shfl_xor(mi[k], mk); }
        #pragma unroll
        for (int k = 0; k < K; ++k) top5_insert(ov[k], oi[k], mv, mi);
    }
    if (lane == 0) {
        #pragma unroll
        for (int k = 0; k < K; ++k) wlist[w][k] = make_float2(mv[k], __int_as_float(mi[k]));
    }
    __syncthreads();
    if (w == 0) {
        #pragma unroll
        for (int k = 0; k < K; ++k) { mv[k] = -1e30f; mi[k] = 0x7fffffff; }
        if (lane < 8) {
            #pragma unroll
            for (int k = 0; k < K; ++k) {
                float2 c = wlist[lane][k];
                mv[k] = c.x; mi[k] = __float_as_int(c.y);
            }
        }
        #pragma unroll
        for (int mk = 1; mk <= 4; mk <<= 1) {
            float ov[K]; int oi[K];
            #pragma unroll
            for (int k = 0; k < K; ++k) { ov[k] = __shfl_xor(mv[k], mk); oi[k] = __shfl_xor(mi[k], mk); }
            #pragma unroll
            for (int k = 0; k < K; ++k) top5_insert(ov[k], oi[k], mv, mi);
        }
        if (lane == 0) {
            #pragma unroll
            for (int k = 0; k < K; ++k) top_idx[b * K + k] = mi[k];
        }
    }
}

// k3: one block per (b,k) row: bottom-m membership of |gal[row,c]*s_f[b,c]|
// (per-row norms are positive constants -> ordering matches the reference's
// normalized products). Plain stores; kernel-boundary coherence (R8 lesson).
__global__ __launch_bounds__(512) void k3_member(const float* __restrict__ s_f,
                                                 const float* __restrict__ gal,
                                                 const int* __restrict__ top_idx,
                                                 unsigned long long* __restrict__ bkmask) {
    __shared__ __align__(16) float pS[D];
    const int p = threadIdx.x;
    const int bk = blockIdx.x;
    const int b = bk / K;
    const int row = top_idx[bk];
    float pv = fabsf(gal[(size_t)row * D + p] * s_f[(size_t)b * D + p]);
    pS[p] = pv;
    __syncthreads();
    int cnt = 0;
    const float4* p4 = reinterpret_cast<const float4*>(pS);
    #pragma unroll 4
    for (int j = 0; j < D / 4; ++j) {
        float4 o = p4[j];
        cnt += (o.x < pv || (o.x == pv && (4 * j + 0) < p)) ? 1 : 0;
        cnt += (o.y < pv || (o.y == pv && (4 * j + 1) < p)) ? 1 : 0;
        cnt += (o.z < pv || (o.z == pv && (4 * j + 2) < p)) ? 1 : 0;
        cnt += (o.w < pv || (o.w == pv && (4 * j + 3) < p)) ? 1 : 0;
    }
    unsigned long long bm = __ballot(cnt < M);
    if ((p & 63) == 0) bkmask[(size_t)bk * 8 + (p >> 6)] = bm;
}

// k4: AND-reduce the 640 per-(b,k) masks, emit the output mask. 40 KB, L2-hot.
__global__ __launch_bounds__(512) void k4_final(const unsigned long long* __restrict__ bkmask,
                                                float* __restrict__ out) {
    const int c = threadIdx.x;
    const int word = c >> 6, bit = c & 63;
    unsigned long long acc = ~0ull;
    for (int bk = 0; bk < B * K; bk += 4) {
        acc &= bkmask[(size_t)bk * 8 + word];
        acc &= bkmask[(size_t)(bk + 1) * 8 + word];
        acc &= bkmask[(size_t)(bk + 2) * 8 + word];
        acc &= bkmask[(size_t)(bk + 3) * 8 + word];
    }
    out[c] = ((acc >> bit) & 1ull) ? 0.0f : 1.0f;
}

extern "C" void kernel_launch(void* const* d_in, const int* in_sizes, int n_in,
                              void* d_out, int out_size, void* d_ws, size_t ws_size,
                              hipStream_t stream) {
    (void)in_sizes; (void)n_in; (void)out_size; (void)ws_size;
    const float* s_f = (const float*)d_in[0];
    const float* t_f = (const float*)d_in[1];
    const float* gal = (const float*)d_in[2];
    float* out = (float*)d_out;

    char* ws = (char*)d_ws;
    const size_t off_frag    = 0;                        // 131072
    const size_t off_partial = 131072;                   // 128*256*5*8 = 1310720
    const size_t off_topidx  = off_partial + 1310720;    // 2560
    const size_t off_bkmask  = off_topidx + 2560;        // 40960

    uint4* frag_t = (uint4*)(ws + off_frag);
    float2* partial = (float2*)(ws + off_partial);
    int* top_idx = (int*)(ws + off_topidx);
    unsigned long long* bkmask = (unsigned long long*)(ws + off_bkmask);

    hipLaunchKernelGGL(k0_tfrag, dim3(16), dim3(512), 0, stream, t_f, frag_t);
    hipLaunchKernelGGL(k1_sims, dim3(NBLK1), dim3(1024), 0, stream, frag_t, gal, partial);
    hipLaunchKernelGGL(k2_merge, dim3(B), dim3(512), 0, stream, partial, top_idx);
    hipLaunchKernelGGL(k3_member, dim3(B * K), dim3(512), 0, stream, s_f, gal, top_idx, bkmask);
    hipLaunchKernelGGL(k4_final, dim3(1), dim3(512), 0, stream, bkmask, out);
}

// Round 12
// 125.740 us; speedup vs baseline: 1.0279x; 1.0279x over previous
//
#include <hip/hip_runtime.h>

#define B 128
#define N 65536
#define D 512
#define K 5
#define M 256              // D * RATIO
#define GPB 256            // gallery rows per block (kernel1)
#define NBLK1 (N / GPB)    // 256 blocks
#define CHR 16             // g-rows per chunk
#define NCHK (GPB / CHR)   // 16

typedef __attribute__((ext_vector_type(8))) short short8;
typedef __attribute__((ext_vector_type(4))) float f32x4;
typedef __attribute__((address_space(1))) const unsigned char as1cu8;
typedef __attribute__((address_space(3))) unsigned char as3u8;

// pack two fp32 -> one u32 of 2 bf16 (truncation) via v_perm_b32.
__device__ __forceinline__ unsigned int pack_bf2(float lo, float hi) {
    return __builtin_amdgcn_perm(__float_as_uint(hi), __float_as_uint(lo), 0x07060302u);
}

__device__ __forceinline__ void top5_insert(float v, int gi, float tv[K], int ti[K]) {
    // descending by value, ties broken by lower index (matches lax.top_k)
    if (v > tv[K - 1] || (v == tv[K - 1] && gi < ti[K - 1])) {
        tv[K - 1] = v; ti[K - 1] = gi;
        #pragma unroll
        for (int k = K - 1; k > 0; --k) {
            bool sw = (tv[k] > tv[k - 1]) || (tv[k] == tv[k - 1] && ti[k] < ti[k - 1]);
            if (sw) {
                float fv = tv[k]; tv[k] = tv[k - 1]; tv[k - 1] = fv;
                int fi = ti[k]; ti[k] = ti[k - 1]; ti[k - 1] = fi;
            }
        }
    }
}

// packed-score insert (meta lives in low 8 mantissa bits; candidates distinct)
__device__ __forceinline__ void pk_insert(float sp, float lst[K]) {
    if (sp > lst[K - 1]) {
        lst[K - 1] = sp;
        #pragma unroll
        for (int k = K - 1; k > 0; --k)
            if (lst[k] > lst[k - 1]) {
                float t2 = lst[k]; lst[k] = lst[k - 1]; lst[k - 1] = t2;
            }
    }
}

// k1: single GEMM kernel, fp32 gallery streamed DIRECTLY via global_load_lds
// with per-lane XOR-swizzled SOURCE addresses (rule #21: linear LDS dest,
// pre-swizzled source, swizzled read). R10/R11 lesson: lane=row register
// loads (16 rows @ 2KB stride / inst) cap delivered BW at ~770 GB/s; here
// every DMA inst is a contiguous 1KB row-segment (XOR permutes only within
// 128B groups -> same cache lines). 16 waves = (bt 0..7) x (k-half 0..1);
// t-fragments in 32 VGPRs/wave (gathered once, t_f is L2-resident 256KB);
// one barrier per 16-row chunk; cross-k-half C sum + norm + top-5 pipelined
// one chunk behind via double-buffered LDS.
__global__ __launch_bounds__(1024, 4) void k1_sims(const float* __restrict__ t_f,
                                                   const float* __restrict__ gal,
                                                   float2* __restrict__ partial) {
    __shared__ __align__(16) char gbuf[2][CHR * 2048];   // 65536 B fp32 chunks
    __shared__ __align__(16) float cbuf_c[2][16][256];   // 32768 B C exchange
    __shared__ __align__(16) float cbuf_n[2][16][16];    //  2048 B norm exchange

    const int tid = threadIdx.x;
    const int blk = blockIdx.x;
    const int lane = tid & 63;
    const int w = tid >> 6;
    const int l15 = lane & 15;
    const int l4 = lane >> 4;
    const int bt = w & 7;     // b-tile (16 b-rows)
    const int kh = w >> 3;    // k-half (ks 0-7 / 8-15)

    const char* gal_b = reinterpret_cast<const char*>(gal);
    const size_t rowbase = ((size_t)blk * GPB) * (D * 4);
    const int lsw = (lane * 16) ^ ((w & 7) << 4);   // swizzled lane offset (row = w)

    // DMA chunk c into gbuf[bi]: wave w stages row w of the chunk (2KB = 2 insts)
    auto DMA = [&](int c, int bi) {
        const char* s0 = gal_b + rowbase + ((size_t)c * CHR + w) * (D * 4) + lsw;
        char* d = &gbuf[bi][w * 2048];
        __builtin_amdgcn_global_load_lds((as1cu8*)s0, (as3u8*)d, 16, 0, 0);
        __builtin_amdgcn_global_load_lds((as1cu8*)(s0 + 1024), (as3u8*)(d + 1024), 16, 0, 0);
    };

    DMA(0, 0);

    // t-fragments: lane holds t[bt*16 + l15][ks*32 + l4*8 .. +8], ks = kh*8+j
    short8 tfr[8];
    {
        const float* tp = t_f + (size_t)(bt * 16 + l15) * D + (kh * 8) * 32 + l4 * 8;
        #pragma unroll
        for (int j = 0; j < 8; ++j) {
            float4 a = *reinterpret_cast<const float4*>(tp + j * 32);
            float4 b = *reinterpret_cast<const float4*>(tp + j * 32 + 4);
            uint4 q;
            q.x = pack_bf2(a.x, a.y); q.y = pack_bf2(a.z, a.w);
            q.z = pack_bf2(b.x, b.y); q.w = pack_bf2(b.z, b.w);
            tfr[j] = *reinterpret_cast<short8*>(&q);
        }
    }

    float lst[K];
    #pragma unroll
    for (int k = 0; k < K; ++k) lst[k] = -1e30f;

    const int xr = (l15 & 7) << 4;
    __syncthreads();   // chunk 0 staged

    for (int c = 0; c < NCHK; ++c) {
        const int bi = c & 1;
        if (c + 1 < NCHK) DMA(c + 1, bi ^ 1);

        // finish previous chunk: sum k-halves, scale, insert (kh==1 waves)
        if (c > 0 && kh == 1) {
            const int pb = bi ^ 1;
            f32x4 c0 = *reinterpret_cast<const f32x4*>(&cbuf_c[pb][bt][lane * 4]);
            f32x4 c1 = *reinterpret_cast<const f32x4*>(&cbuf_c[pb][8 + bt][lane * 4]);
            float4 n0 = *reinterpret_cast<const float4*>(&cbuf_n[pb][bt][l4 * 4]);
            float4 n1 = *reinterpret_cast<const float4*>(&cbuf_n[pb][8 + bt][l4 * 4]);
            float nn[4] = {n0.x + n1.x, n0.y + n1.y, n0.z + n1.z, n0.w + n1.w};
            #pragma unroll
            for (int r = 0; r < 4; ++r) {
                float s = (c0[r] + c1[r]) * rsqrtf(fmaxf(nn[r], 1e-24f));
                unsigned meta = (unsigned)((c - 1) * CHR + l4 * 4 + r);
                float sp = __uint_as_float((__float_as_uint(s) & 0xFFFFFF00u) | meta);
                pk_insert(sp, lst);
            }
        }

        // compute chunk c: 8 k-slices (this wave's k-half)
        f32x4 acc = (f32x4)0.0f;
        float nrm = 0.0f;
        const char* gb = &gbuf[bi][0];
        #pragma unroll
        for (int j = 0; j < 8; ++j) {
            const int ks = kh * 8 + j;
            const int base = l15 * 2048 + ks * 128;
            float4 a0 = *reinterpret_cast<const float4*>(gb + base + ((l4 * 32) ^ xr));
            float4 a1 = *reinterpret_cast<const float4*>(gb + base + ((l4 * 32 + 16) ^ xr));
            nrm = fmaf(a0.x, a0.x, nrm); nrm = fmaf(a0.y, a0.y, nrm);
            nrm = fmaf(a0.z, a0.z, nrm); nrm = fmaf(a0.w, a0.w, nrm);
            nrm = fmaf(a1.x, a1.x, nrm); nrm = fmaf(a1.y, a1.y, nrm);
            nrm = fmaf(a1.z, a1.z, nrm); nrm = fmaf(a1.w, a1.w, nrm);
            uint4 q;
            q.x = pack_bf2(a0.x, a0.y); q.y = pack_bf2(a0.z, a0.w);
            q.z = pack_bf2(a1.x, a1.y); q.w = pack_bf2(a1.z, a1.w);
            short8 af = *reinterpret_cast<short8*>(&q);
            acc = __builtin_amdgcn_mfma_f32_16x16x32_bf16(af, tfr[j], acc, 0, 0, 0);
        }
        // half-row norms: sum over l4 quarters (this k-half)
        nrm += __shfl_xor(nrm, 16);
        nrm += __shfl_xor(nrm, 32);
        if (lane < CHR) cbuf_n[bi][w][lane] = nrm;
        *reinterpret_cast<f32x4*>(&cbuf_c[bi][w][lane * 4]) = acc;

        __syncthreads();   // cbuf visible + next chunk's DMA drained
    }

    // epilogue: finish chunk NCHK-1
    if (kh == 1) {
        const int pb = (NCHK - 1) & 1;
        f32x4 c0 = *reinterpret_cast<const f32x4*>(&cbuf_c[pb][bt][lane * 4]);
        f32x4 c1 = *reinterpret_cast<const f32x4*>(&cbuf_c[pb][8 + bt][lane * 4]);
        float4 n0 = *reinterpret_cast<const float4*>(&cbuf_n[pb][bt][l4 * 4]);
        float4 n1 = *reinterpret_cast<const float4*>(&cbuf_n[pb][8 + bt][l4 * 4]);
        float nn[4] = {n0.x + n1.x, n0.y + n1.y, n0.z + n1.z, n0.w + n1.w};
        #pragma unroll
        for (int r = 0; r < 4; ++r) {
            float s = (c0[r] + c1[r]) * rsqrtf(fmaxf(nn[r], 1e-24f));
            unsigned meta = (unsigned)((NCHK - 1) * CHR + l4 * 4 + r);
            float sp = __uint_as_float((__float_as_uint(s) & 0xFFFFFF00u) | meta);
            pk_insert(sp, lst);
        }
    }

    // merge per-b lists across the 4 l4 lanes (masks 16, 32)
    #pragma unroll
    for (int mk = 16; mk <= 32; mk <<= 1) {
        float inc[K];
        #pragma unroll
        for (int k = 0; k < K; ++k) inc[k] = __shfl_xor(lst[k], mk);
        #pragma unroll
        for (int k = 0; k < K; ++k) pk_insert(inc[k], lst);
    }

    if (kh == 1 && l4 == 0) {
        const int b = bt * 16 + l15;
        #pragma unroll
        for (int k = 0; k < K; ++k) {
            unsigned sp = __float_as_uint(lst[k]);
            int g = blk * GPB + (int)(sp & 0xFFu);
            partial[((size_t)b * NBLK1 + blk) * K + k] = make_float2(lst[k], __int_as_float(g));
        }
    }
}

// k2: merge 256 partial top-5 lists per batch row -> top_idx. Shuffle-first.
__global__ __launch_bounds__(512) void k2_merge(const float2* __restrict__ partial,
                                                int* __restrict__ top_idx) {
    __shared__ float2 wlist[8][K];
    const int b = blockIdx.x;
    const int p = threadIdx.x;
    const int lane = p & 63;
    const int w = p >> 6;

    float mv[K]; int mi[K];
    #pragma unroll
    for (int k = 0; k < K; ++k) { mv[k] = -1e30f; mi[k] = 0x7fffffff; }
    if (p < NBLK1) {
        #pragma unroll
        for (int k = 0; k < K; ++k) {
            float2 c = partial[((size_t)b * NBLK1 + p) * K + k];
            mv[k] = c.x; mi[k] = __float_as_int(c.y);
        }
    }
    #pragma unroll
    for (int mk = 1; mk <= 32; mk <<= 1) {
        float ov[K]; int oi[K];
        #pragma unroll
        for (int k = 0; k < K; ++k) { ov[k] = __shfl_xor(mv[k], mk); oi[k] = __shfl_xor(mi[k], mk); }
        #pragma unroll
        for (int k = 0; k < K; ++k) top5_insert(ov[k], oi[k], mv, mi);
    }
    if (lane == 0) {
        #pragma unroll
        for (int k = 0; k < K; ++k) wlist[w][k] = make_float2(mv[k], __int_as_float(mi[k]));
    }
    __syncthreads();
    if (w == 0) {
        #pragma unroll
        for (int k = 0; k < K; ++k) { mv[k] = -1e30f; mi[k] = 0x7fffffff; }
        if (lane < 8) {
            #pragma unroll
            for (int k = 0; k < K; ++k) {
                float2 c = wlist[lane][k];
                mv[k] = c.x; mi[k] = __float_as_int(c.y);
            }
        }
        #pragma unroll
        for (int mk = 1; mk <= 4; mk <<= 1) {
            float ov[K]; int oi[K];
            #pragma unroll
            for (int k = 0; k < K; ++k) { ov[k] = __shfl_xor(mv[k], mk); oi[k] = __shfl_xor(mi[k], mk); }
            #pragma unroll
            for (int k = 0; k < K; ++k) top5_insert(ov[k], oi[k], mv, mi);
        }
        if (lane == 0) {
            #pragma unroll
            for (int k = 0; k < K; ++k) top_idx[b * K + k] = mi[k];
        }
    }
}

// k3: one block per (b,k) row: bottom-m membership of |gal[row,c]*s_f[b,c]|
// (per-row norms are positive constants -> ordering matches the reference's
// normalized products). Plain stores; kernel-boundary coherence (R8 lesson).
__global__ __launch_bounds__(512) void k3_member(const float* __restrict__ s_f,
                                                 const float* __restrict__ gal,
                                                 const int* __restrict__ top_idx,
                                                 unsigned long long* __restrict__ bkmask) {
    __shared__ __align__(16) float pS[D];
    const int p = threadIdx.x;
    const int bk = blockIdx.x;
    const int b = bk / K;
    const int row = top_idx[bk];
    float pv = fabsf(gal[(size_t)row * D + p] * s_f[(size_t)b * D + p]);
    pS[p] = pv;
    __syncthreads();
    int cnt = 0;
    const float4* p4 = reinterpret_cast<const float4*>(pS);
    #pragma unroll 4
    for (int j = 0; j < D / 4; ++j) {
        float4 o = p4[j];
        cnt += (o.x < pv || (o.x == pv && (4 * j + 0) < p)) ? 1 : 0;
        cnt += (o.y < pv || (o.y == pv && (4 * j + 1) < p)) ? 1 : 0;
        cnt += (o.z < pv || (o.z == pv && (4 * j + 2) < p)) ? 1 : 0;
        cnt += (o.w < pv || (o.w == pv && (4 * j + 3) < p)) ? 1 : 0;
    }
    unsigned long long bm = __ballot(cnt < M);
    if ((p & 63) == 0) bkmask[(size_t)bk * 8 + (p >> 6)] = bm;
}

// k4: AND-reduce the 640 per-(b,k) masks, emit the output mask. 40 KB, L2-hot.
__global__ __launch_bounds__(512) void k4_final(const unsigned long long* __restrict__ bkmask,
                                                float* __restrict__ out) {
    const int c = threadIdx.x;
    const int word = c >> 6, bit = c & 63;
    unsigned long long acc = ~0ull;
    for (int bk = 0; bk < B * K; bk += 4) {
        acc &= bkmask[(size_t)bk * 8 + word];
        acc &= bkmask[(size_t)(bk + 1) * 8 + word];
        acc &= bkmask[(size_t)(bk + 2) * 8 + word];
        acc &= bkmask[(size_t)(bk + 3) * 8 + word];
    }
    out[c] = ((acc >> bit) & 1ull) ? 0.0f : 1.0f;
}

extern "C" void kernel_launch(void* const* d_in, const int* in_sizes, int n_in,
                              void* d_out, int out_size, void* d_ws, size_t ws_size,
                              hipStream_t stream) {
    (void)in_sizes; (void)n_in; (void)out_size; (void)ws_size;
    const float* s_f = (const float*)d_in[0];
    const float* t_f = (const float*)d_in[1];
    const float* gal = (const float*)d_in[2];
    float* out = (float*)d_out;

    char* ws = (char*)d_ws;
    const size_t off_partial = 0;                        // 128*256*5*8 = 1310720
    const size_t off_topidx  = off_partial + 1310720;    // 2560
    const size_t off_bkmask  = off_topidx + 2560;        // 40960

    float2* partial = (float2*)(ws + off_partial);
    int* top_idx = (int*)(ws + off_topidx);
    unsigned long long* bkmask = (unsigned long long*)(ws + off_bkmask);

    hipLaunchKernelGGL(k1_sims, dim3(NBLK1), dim3(1024), 0, stream, t_f, gal, partial);
    hipLaunchKernelGGL(k2_merge, dim3(B), dim3(512), 0, stream, partial, top_idx);
    hipLaunchKernelGGL(k3_member, dim3(B * K), dim3(512), 0, stream, s_f, gal, top_idx, bkmask);
    hipLaunchKernelGGL(k4_final, dim3(1), dim3(512), 0, stream, bkmask, out);
}